// Round 8
// baseline (279.944 us; speedup 1.0000x reference)
//
#include <hip/hip_runtime.h>

// GroupBatchNorm: B=512, C=65536, G=4096, fp32 in/out.
// R10: R9's partials-free pipeline + harness-safe zeroing.
//   R9 failed the statefulness tripwire: it zeroed group accums at the END
//   of norm_k (block 0) and relied on that across graph replays -- the
//   cross-launch invariant broke (stable wrong steady state, absmax 4.84).
//   RULE: never carry required state across kernel_launch calls; zero at the
//   START of the sequence, consume strictly later (R4/R7/R8 all passed this
//   way).
// Pipeline (4 launches):
//   zero_k  : zero 48 KB group accums (16 blocks)
//   stats_k : fused colsum+gsum in registers -- thread owns 4 channels,
//             reduces 128 rows (8-deep float4 batches), 8 global atomics.
//             No 16 MB partials round-trip (saves 32 MB traffic vs R8).
//   cfinal_k: per-channel scale/shift gather (R4-proven)
//   norm_k  : pure streaming normalize, one float4/thread (R4-proven),
//             NO persistent-state side effects.

constexpr int B = 512;
constexpr int C = 65536;
constexpr int G = 4096;
constexpr int Q = C / 4;            // 16384 channel-quads (pow2)
constexpr int CHUNKS = 4;           // row chunks in stats_k
constexpr int RPC = B / CHUNKS;     // 128 rows per chunk
constexpr int BATCH = 8;            // float4 loads in flight per thread
#define EPS 1e-5f

// Device-global scratch. Zeroed by zero_k at the start of EVERY launch
// sequence -- no reliance on .bss init or prior-launch cleanup.
__device__ float g_gsum[G];
__device__ float g_gsum2[G];
__device__ float g_gcnt[G];
__device__ float g_cscale[C];
__device__ float g_cshift[C];

// ---- K0: zero group accumulators. grid = 16 blocks.
__global__ __launch_bounds__(256) void zero_k() {
    int i = blockIdx.x * 256 + threadIdx.x;
    if (i < G) {
        g_gsum[i] = 0.0f;
        g_gsum2[i] = 0.0f;
        g_gcnt[i] = 0.0f;
    }
}

// ---- K1: fused colsum+gsum. grid = 64 col-blocks x 4 chunks = 256 blocks.
// Thread reduces its 4 channels over 128 rows entirely in registers, then
// scatters straight into group accumulators (no partials arrays).
__global__ __launch_bounds__(256) void stats_k(const float* __restrict__ x,
                                               const int* __restrict__ cg) {
    const int nblk_c = Q / 256;                                // 64
    const int c4 = (blockIdx.x % nblk_c) * 256 + threadIdx.x;  // channel-quad
    const int chunk = blockIdx.x / nblk_c;                     // 4 chunks
    const float4* __restrict__ xp =
        (const float4*)(x + (size_t)chunk * RPC * C) + c4;
    float4 s = {0.f, 0.f, 0.f, 0.f};
    float4 s2 = {0.f, 0.f, 0.f, 0.f};
    float4 vbuf[BATCH];
    for (int base = 0; base < RPC; base += BATCH) {
#pragma unroll
        for (int j = 0; j < BATCH; ++j)
            vbuf[j] = xp[(size_t)(base + j) * Q];
#pragma unroll
        for (int j = 0; j < BATCH; ++j) {
            float4 v = vbuf[j];
            s.x += v.x; s.y += v.y; s.z += v.z; s.w += v.w;
            s2.x = fmaf(v.x, v.x, s2.x);
            s2.y = fmaf(v.y, v.y, s2.y);
            s2.z = fmaf(v.z, v.z, s2.z);
            s2.w = fmaf(v.w, v.w, s2.w);
        }
    }
    const int4 gq = ((const int4*)cg)[c4];
    atomicAdd(&g_gsum[gq.x], s.x);  atomicAdd(&g_gsum2[gq.x], s2.x);
    atomicAdd(&g_gsum[gq.y], s.y);  atomicAdd(&g_gsum2[gq.y], s2.y);
    atomicAdd(&g_gsum[gq.z], s.z);  atomicAdd(&g_gsum2[gq.z], s2.z);
    atomicAdd(&g_gsum[gq.w], s.w);  atomicAdd(&g_gsum2[gq.w], s2.w);
    if (chunk == 0) {
        atomicAdd(&g_gcnt[gq.x], 1.0f);
        atomicAdd(&g_gcnt[gq.y], 1.0f);
        atomicAdd(&g_gcnt[gq.z], 1.0f);
        atomicAdd(&g_gcnt[gq.w], 1.0f);
    }
}

// ---- K2: per-channel fused scale/shift (gather ONCE per channel).
__global__ __launch_bounds__(256) void cfinal_k(const int* __restrict__ cg,
                                                const float* __restrict__ gamma,
                                                const float* __restrict__ beta) {
    const int c = blockIdx.x * 256 + threadIdx.x;
    const int g = cg[c];
    float cnt = fmaxf(g_gcnt[g] * (float)B, 1.0f);
    float mean = g_gsum[g] / cnt;
    float var = g_gsum2[g] / cnt - mean * mean;
    float inv = 1.0f / sqrtf(var + EPS);
    float sc = gamma[g] * inv;
    g_cscale[c] = sc;
    g_cshift[c] = fmaf(-mean, sc, beta[g]);
}

// ---- K3: streaming normalize, one float4 per thread; scale/shift read
// coalesced from L2-hot 512 KB tables. grid = 32768 blocks. Stateless.
__global__ __launch_bounds__(256) void norm_k(const float* __restrict__ x,
                                              float* __restrict__ out) {
    const size_t i = (size_t)blockIdx.x * 256 + threadIdx.x;
    const int c4 = (int)(i & (Q - 1));  // channel-quad (pow2)
    float4 xv = ((const float4*)x)[i];
    float4 s = ((const float4*)g_cscale)[c4];
    float4 t = ((const float4*)g_cshift)[c4];
    float4 o;
    o.x = fmaf(xv.x, s.x, t.x);
    o.y = fmaf(xv.y, s.y, t.y);
    o.z = fmaf(xv.z, s.z, t.z);
    o.w = fmaf(xv.w, s.w, t.w);
    ((float4*)out)[i] = o;
}

extern "C" void kernel_launch(void* const* d_in, const int* in_sizes, int n_in,
                              void* d_out, int out_size, void* d_ws, size_t ws_size,
                              hipStream_t stream) {
    const float* x = (const float*)d_in[0];
    const int* cg = (const int*)d_in[1];
    const float* gamma = (const float*)d_in[2];
    const float* beta = (const float*)d_in[3];
    float* out = (float*)d_out;
    (void)d_ws; (void)ws_size; (void)in_sizes; (void)n_in; (void)out_size;

    zero_k<<<(G + 255) / 256, 256, 0, stream>>>();
    stats_k<<<(Q / 256) * CHUNKS, 256, 0, stream>>>(x, cg);
    cfinal_k<<<C / 256, 256, 0, stream>>>(cg, gamma, beta);
    norm_k<<<(B * C / 4) / 256, 256, 0, stream>>>(x, out);
}